// Round 5
// baseline (1561.914 us; speedup 1.0000x reference)
//
#include <hip/hip_runtime.h>
#include <math.h>

#define NR 8192
#define NPICK 4096
#define SDF_THR_C 5e-5f

// output layout (floats)
#define OUT_DPRED 0
#define OUT_SDFL  8192
#define OUT_SAMP  16384
#define OUT_FIN   139264   // 16384 + 40960*3

typedef __attribute__((ext_vector_type(8))) short short8v;
typedef __attribute__((ext_vector_type(4))) float f32x4;

#define SK  320   // activation plane k-stride (shorts)
#define SKB 640   // bytes per plane row

struct Wptrs { const float* w[8]; };
struct MegaP {
  const float* b[8];
  const float* b8;
  const float* w8;
  const unsigned short* WThi;
  const unsigned short* WTlo;
  const float* ray0; const float* rdir; const float* frand;
  float* ptrack; float* out;
};

__device__ __forceinline__ unsigned short f2bf(float f) {
  unsigned int u = __float_as_uint(f);
  unsigned int r = u + 0x7FFFu + ((u >> 16) & 1u);
  return (unsigned short)(r >> 16);
}
__device__ __forceinline__ float bf2f(unsigned short h) {
  return __uint_as_float(((unsigned int)h) << 16);
}
// NOTE: keep EXACTLY round-3's math (log1pf/expf, sinf/cosf below). Fast
// transcendentals perturbed borderline finish_mask rays -> failed round 4.
__device__ __forceinline__ float softplus100(float h) {
  float z = 100.0f * h;
  return (fmaxf(z, 0.0f) + log1pf(expf(-fabsf(z)))) * 0.01f;
}

// ---------------------------------------------------------------------------
// prep: transpose + bf16 hi/lo split of weights. WT[col][Kp] per layer.
// ---------------------------------------------------------------------------
__global__ void prep_transpose(Wptrs wp, unsigned short* __restrict__ WThi,
                               unsigned short* __restrict__ WTlo)
{
  __shared__ unsigned short sh[64 * 66];
  __shared__ unsigned short sl[64 * 66];
  const int Kreal[8] = {39,256,256,256,295,256,256,256};
  const int Kp[8]    = {64,256,256,256,320,256,256,256};
  const int WB[8]    = {0,16384,81920,147456,212992,294912,360448,425984};
  const int cum[9]   = {0,4,20,36,52,72,88,104,120};
  int b = blockIdx.x;
  int l = 0;
  while (l < 7 && b >= cum[l + 1]) ++l;
  int tile = b - cum[l];
  int tk_n = Kp[l] >> 6;
  int tk = tile % tk_n, tc = tile / tk_n;
  const float* __restrict__ W = wp.w[l];
  int t = threadIdx.x;
  #pragma unroll
  for (int i = 0; i < 16; ++i) {
    int id = t + i * 256;
    int kl = id >> 6, cl = id & 63;
    int k = tk * 64 + kl, c = tc * 64 + cl;
    float v = (k < Kreal[l]) ? W[k * 256 + c] : 0.0f;
    unsigned short h = f2bf(v);
    unsigned short lo = f2bf(v - bf2f(h));
    sh[kl * 66 + cl] = h;
    sl[kl * 66 + cl] = lo;
  }
  __syncthreads();
  #pragma unroll
  for (int i = 0; i < 16; ++i) {
    int id = t + i * 256;
    int cl = id >> 6, kl = id & 63;
    size_t o = (size_t)WB[l] + (size_t)(tc * 64 + cl) * Kp[l] + tk * 64 + kl;
    WThi[o] = sh[kl * 66 + cl];
    WTlo[o] = sl[kl * 66 + cl];
  }
}

// ---------------------------------------------------------------------------
// One hidden layer: pipelined MFMA (double-buffered A/B frags) + epilogue.
// 32 rows x 256 cols per block; wave wv owns cols [wv*64, wv*64+64).
// MFMA issue order identical to round 3 -> bit-identical accumulation.
// ---------------------------------------------------------------------------
template<int NKS, int KPL>
__device__ __forceinline__ void layer_full(
    const unsigned short* __restrict__ bh, const unsigned short* __restrict__ bl,
    const float* __restrict__ brow,
    unsigned short* Ah, unsigned short* Al,
    int lq, int lr, int cw, int swA)
{
  const char* ahc = (const char*)Ah;
  const char* alc = (const char*)Al;
  f32x4 acc[2][4];
  #pragma unroll
  for (int i = 0; i < 2; ++i)
    #pragma unroll
    for (int j = 0; j < 4; ++j)
      acc[i][j] = (f32x4){0.f, 0.f, 0.f, 0.f};

  const unsigned short* pbh[4];
  const unsigned short* pbl[4];
  #pragma unroll
  for (int ct = 0; ct < 4; ++ct) {
    int col = cw + ct * 16 + lr;
    pbh[ct] = bh + (size_t)col * KPL + lq * 8;
    pbl[ct] = bl + (size_t)col * KPL + lq * 8;
  }

  short8v B[2][4][2];   // [buf][ct][hi/lo]
  short8v A[2][2][2];   // [buf][row-tile][hi/lo]
  #pragma unroll
  for (int ct = 0; ct < 4; ++ct) {
    B[0][ct][0] = *(const short8v*)(pbh[ct]);
    B[0][ct][1] = *(const short8v*)(pbl[ct]);
  }
  {
    int ax = (lq * 16) ^ swA;
    A[0][0][0] = *(const short8v*)(ahc + lr * SKB + ax);
    A[0][1][0] = *(const short8v*)(ahc + (16 + lr) * SKB + ax);
    A[0][0][1] = *(const short8v*)(alc + lr * SKB + ax);
    A[0][1][1] = *(const short8v*)(alc + (16 + lr) * SKB + ax);
  }

  #pragma unroll
  for (int ks = 0; ks < NKS; ++ks) {
    const int cur = ks & 1, nxt = cur ^ 1;
    if (ks + 1 < NKS) {
      #pragma unroll
      for (int ct = 0; ct < 4; ++ct) {
        B[nxt][ct][0] = *(const short8v*)(pbh[ct] + (ks + 1) * 32);
        B[nxt][ct][1] = *(const short8v*)(pbl[ct] + (ks + 1) * 32);
      }
      int ax = ((ks + 1) * 64 + lq * 16) ^ swA;
      A[nxt][0][0] = *(const short8v*)(ahc + lr * SKB + ax);
      A[nxt][1][0] = *(const short8v*)(ahc + (16 + lr) * SKB + ax);
      A[nxt][0][1] = *(const short8v*)(alc + lr * SKB + ax);
      A[nxt][1][1] = *(const short8v*)(alc + (16 + lr) * SKB + ax);
    }
    #pragma unroll
    for (int ct = 0; ct < 4; ++ct) {
      acc[0][ct] = __builtin_amdgcn_mfma_f32_16x16x32_bf16(A[cur][0][0], B[cur][ct][0], acc[0][ct], 0, 0, 0);
      acc[0][ct] = __builtin_amdgcn_mfma_f32_16x16x32_bf16(A[cur][0][1], B[cur][ct][0], acc[0][ct], 0, 0, 0);
      acc[0][ct] = __builtin_amdgcn_mfma_f32_16x16x32_bf16(A[cur][0][0], B[cur][ct][1], acc[0][ct], 0, 0, 0);
      acc[1][ct] = __builtin_amdgcn_mfma_f32_16x16x32_bf16(A[cur][1][0], B[cur][ct][0], acc[1][ct], 0, 0, 0);
      acc[1][ct] = __builtin_amdgcn_mfma_f32_16x16x32_bf16(A[cur][1][1], B[cur][ct][0], acc[1][ct], 0, 0, 0);
      acc[1][ct] = __builtin_amdgcn_mfma_f32_16x16x32_bf16(A[cur][1][0], B[cur][ct][1], acc[1][ct], 0, 0, 0);
    }
  }

  __syncthreads();   // all plane reads of this layer complete

  char* ahw = (char*)Ah;
  char* alw = (char*)Al;
  #pragma unroll
  for (int ct = 0; ct < 4; ++ct) {
    int col = cw + ct * 16 + lr;
    float bv = brow[col];
    int cb2 = col * 2;
    #pragma unroll
    for (int rt = 0; rt < 2; ++rt) {
      #pragma unroll
      for (int r = 0; r < 4; ++r) {
        float h = softplus100(acc[rt][ct][r] + bv);
        unsigned short hh = f2bf(h);
        unsigned short hl = f2bf(h - bf2f(hh));
        int row = rt * 16 + lq * 4 + r;
        int addr = row * SKB + (cb2 ^ ((row & 7) << 4));
        *(unsigned short*)(ahw + addr) = hh;
        *(unsigned short*)(alw + addr) = hl;
      }
    }
  }
  __syncthreads();
}

// ---------------------------------------------------------------------------
// Mega kernel: 16 rays/block, full 8-step sphere trace fused.
// Rows 0-15 = s-points, rows 16-31 = e-points of rays rayb..rayb+15.
// ---------------------------------------------------------------------------
__global__ __launch_bounds__(256, 2)
void mega_kernel(MegaP P)
{
  __shared__ __align__(16) unsigned short Ah[32 * SK];
  __shared__ __align__(16) unsigned short Al[32 * SK];
  __shared__ float enc[32 * 40];
  __shared__ float red[8 * 32];
  __shared__ float bL[8][256];
  __shared__ float wsm[256];
  __shared__ float posL[32][3];
  __shared__ float sdfv[32];
  __shared__ float stF[8][16];  // 0:tmn 1:tmx 2:accS 3:accE 4:ns 5:ne 6:ssum 7:lastraw
  __shared__ int   stI[4][16];  // 0:mselS 1:mselE 2:mcarS 3:mcarE

  const int WBA[8] = {0,16384,81920,147456,212992,294912,360448,425984};
  const int t = threadIdx.x;
  const int rayb = blockIdx.x * 16;

  // stage biases + w8 column 0
  #pragma unroll
  for (int l = 0; l < 8; ++l) bL[l][t] = P.b[l][t];
  wsm[t] = P.w8[(size_t)t * 257];

  if (t < 16) {
    int ray = rayb + t;
    float ox = P.ray0[3*ray], oy = P.ray0[3*ray+1], oz = P.ray0[3*ray+2];
    float dx = P.rdir[3*ray], dy = P.rdir[3*ray+1], dz = P.rdir[3*ray+2];
    float ix = 1.0f/dx, iy = 1.0f/dy, iz = 1.0f/dz;
    float t1x = (-1.0f - ox)*ix, t2x = (1.0f - ox)*ix;
    float t1y = (-1.0f - oy)*iy, t2y = (1.0f - oy)*iy;
    float t1z = (-1.0f - oz)*iz, t2z = (1.0f - oz)*iz;
    float tmn = fmaxf(fmaxf(fminf(t1x,t2x), fminf(t1y,t2y)), fminf(t1z,t2z));
    float tmx = fminf(fminf(fmaxf(t1x,t2x), fmaxf(t1y,t2y)), fmaxf(t1z,t2z));
    tmn = fmaxf(tmn, 0.0f);
    stF[0][t] = tmn; stF[1][t] = tmx;
    stF[2][t] = tmn; stF[3][t] = tmx;   // acc_s, acc_e
    stF[6][t] = 0.0f;
    stI[0][t] = 1; stI[1][t] = 1; stI[2][t] = 1; stI[3][t] = 1;
    posL[t][0]      = ox + tmn*dx; posL[t][1]      = oy + tmn*dy; posL[t][2]      = oz + tmn*dz;
    posL[16 + t][0] = ox + tmx*dx; posL[16 + t][1] = oy + tmx*dy; posL[16 + t][2] = oz + tmx*dz;
  }
  __syncthreads();

  const int lane = t & 63, wv = t >> 6;
  const int lq = lane >> 4, lr = lane & 15;
  const int cw = wv * 64;
  const char* ahc = (const char*)Ah;
  const char* alc = (const char*)Al;
  const int swA = (lr & 7) << 4;

  #pragma unroll 1
  for (int ev = 0; ev < 8; ++ev) {
    // ---- ptrack[ev] = p_s entering this step (posL rows 0-15)
    if (t < 48) {
      int rr = t / 3, c = t - rr * 3;
      P.ptrack[(size_t)(rayb + rr) * 24 + ev * 3 + c] = posL[rr][c];
    }
    // ---- embed (round-3 sinf/cosf — do NOT substitute fast versions)
    if (t < 32) {
      float x = posL[t][0], y = posL[t][1], z = posL[t][2];
      float xn = ((x + 1.0f) * 0.5f) * 2.0f - 1.0f;
      float yn = ((y + 1.0f) * 0.5f) * 2.0f - 1.0f;
      float zn = ((z + 1.0f) * 0.5f) * 2.0f - 1.0f;
      float* row = enc + t * 40;
      row[0] = xn; row[1] = yn; row[2] = zn;
      float f = 1.0f;
      for (int lf = 0; lf < 6; ++lf) {
        float ax = xn * f, ay = yn * f, az = zn * f;
        row[3  + lf*3 + 0] = sinf(ax);
        row[3  + lf*3 + 1] = sinf(ay);
        row[3  + lf*3 + 2] = sinf(az);
        row[21 + lf*3 + 0] = cosf(ax);
        row[21 + lf*3 + 1] = cosf(ay);
        row[21 + lf*3 + 2] = cosf(az);
        f *= 2.0f;
      }
    }
    __syncthreads();

    // ---- scatter enc (bf16 hi/lo) to planes: k in [0,64) and [256,320)
    {
      char* ahp = (char*)Ah;
      char* alp = (char*)Al;
      int row = t >> 3, c8 = t & 7;
      int sw = (row & 7) << 4;
      #pragma unroll
      for (int reg = 0; reg < 2; ++reg) {
        int koff = reg ? 256 : 0;
        #pragma unroll
        for (int e = 0; e < 8; e += 2) {
          int kl = c8 * 8 + e;
          float v0 = (kl     < 39) ? enc[row * 40 + kl]     : 0.0f;
          float v1 = (kl + 1 < 39) ? enc[row * 40 + kl + 1] : 0.0f;
          unsigned short h0 = f2bf(v0), h1 = f2bf(v1);
          unsigned short q0 = f2bf(v0 - bf2f(h0)), q1 = f2bf(v1 - bf2f(h1));
          int addr = row * SKB + (((koff + kl) * 2) ^ sw);
          *(unsigned int*)(ahp + addr) = (unsigned)h0 | ((unsigned)h1 << 16);
          *(unsigned int*)(alp + addr) = (unsigned)q0 | ((unsigned)q1 << 16);
        }
      }
    }
    __syncthreads();

    // ---- layers 0..7
    layer_full<2, 64>(P.WThi + WBA[0], P.WTlo + WBA[0], bL[0], Ah, Al, lq, lr, cw, swA);
    #pragma unroll 1
    for (int l = 1; l < 8; ++l) {
      if (l == 4)
        layer_full<10, 320>(P.WThi + WBA[4], P.WTlo + WBA[4], bL[4], Ah, Al, lq, lr, cw, swA);
      else
        layer_full<8, 256>(P.WThi + WBA[l], P.WTlo + WBA[l], bL[l], Ah, Al, lq, lr, cw, swA);
    }

    // ---- layer 8: column 0 only
    {
      int r = t & 31, part = t >> 5;
      int sw = (r & 7) << 4;
      float s = 0.0f;
      #pragma unroll
      for (int c = 0; c < 4; ++c) {
        int k = part * 32 + c * 8;
        int addr = r * SKB + ((k * 2) ^ sw);
        short8v vh = *(const short8v*)(ahc + addr);
        short8v vl = *(const short8v*)(alc + addr);
        #pragma unroll
        for (int e = 0; e < 8; ++e) {
          float h = bf2f((unsigned short)vh[e]) + bf2f((unsigned short)vl[e]);
          s = fmaf(h, wsm[k + e], s);
        }
      }
      red[part * 32 + r] = s;
      __syncthreads();
      if (t < 32) {
        float tot = P.b8[0];
        #pragma unroll
        for (int p = 0; p < 8; ++p) tot += red[p * 32 + t];
        sdfv[t] = tot;
      }
      __syncthreads();
    }

    // ---- march step ev (per-ray, threads 0-15)
    if (t < 16) {
      int ray = rayb + t;
      float raw_s = sdfv[t], raw_e = sdfv[16 + t];
      stF[6][t] += raw_s;                 // ssum
      float ns, ne;
      if (ev == 0) { ns = raw_s; ne = raw_e; }
      else {
        ns = stF[4][t]; ne = stF[5][t];
        ns = stI[0][t] ? raw_s : ns;      // select with pre-ok mask of step ev-1
        ne = stI[1][t] ? raw_e : ne;
      }
      if (ev == 7) stF[7][t] = raw_s;     // sdf_tracks[:, -1]
      int ms = stI[2][t], me = stI[3][t];
      float tmx = stF[1][t];
      float cs = (fabsf(ns) <= SDF_THR_C) ? 0.0f : ns;
      float ce = (fabsf(ne) <= SDF_THR_C) ? 0.0f : ne;
      ms = ms & ((fabsf(cs) > SDF_THR_C) ? 1 : 0);
      me = me & ((fabsf(ce) > SDF_THR_C) ? 1 : 0);
      float as_ = fminf(stF[2][t] + cs, tmx);
      float ae  = fminf(stF[3][t] + ce, tmx);
      stF[2][t] = as_; stF[3][t] = ae;
      stF[4][t] = ns;  stF[5][t] = ne;
      int ok = (as_ < ae) ? 1 : 0;
      stI[0][t] = ms;       stI[1][t] = me;       // pre-ok (select masks)
      stI[2][t] = ms & ok;  stI[3][t] = me & ok;  // carry masks
      float ox = P.ray0[3*ray], oy = P.ray0[3*ray+1], oz = P.ray0[3*ray+2];
      float dx = P.rdir[3*ray], dy = P.rdir[3*ray+1], dz = P.rdir[3*ray+2];
      posL[t][0]      = ox + as_*dx; posL[t][1]      = oy + as_*dy; posL[t][2]      = oz + as_*dz;
      posL[16 + t][0] = ox + ae*dx;  posL[16 + t][1] = oy + ae*dy;  posL[16 + t][2] = oz + ae*dz;
    }
    __syncthreads();
  }

  // ---- per-ray outputs
  if (t < 16) {
    int ray = rayb + t;
    float tmn = stF[0][t], tmx = stF[1][t];
    float ssum = stF[6][t], last = stF[7][t];
    P.out[OUT_DPRED + ray] = fminf(ssum + tmn, tmx);
    P.out[OUT_SDFL + ray] = last;
    P.out[OUT_FIN + ray] = (fabsf(last) < 0.0015625f) ? 1.0f : 0.0f;
    float du = fminf(1.5f * stF[3][t], tmx);
    float fr = P.frand[ray];
    float dsm = (1.0f - fr) * du + fr * tmn;
    float ox = P.ray0[3*ray], oy = P.ray0[3*ray+1], oz = P.ray0[3*ray+2];
    float dx = P.rdir[3*ray], dy = P.rdir[3*ray+1], dz = P.rdir[3*ray+2];
    int o2 = OUT_SAMP + 98304 + 3 * ray;
    P.out[o2+0] = ox + dsm*dx;
    P.out[o2+1] = oy + dsm*dy;
    P.out[o2+2] = oz + dsm*dz;
  }
}

// ---------------------------------------------------------------------------
// gather: picked track points (needs all ptrack complete)
// ---------------------------------------------------------------------------
__global__ void gather_kernel(const int* __restrict__ pick, const float* __restrict__ ptrack,
                              float* __restrict__ out)
{
  int i = blockIdx.x * 256 + threadIdx.x;
  if (i >= NPICK) return;
  int ray = pick[i];
  #pragma unroll
  for (int j = 0; j < 24; ++j)
    out[OUT_SAMP + i * 24 + j] = ptrack[(size_t)ray * 24 + j];
}

// ---------------------------------------------------------------------------
extern "C" void kernel_launch(void* const* d_in, const int* in_sizes, int n_in,
                              void* d_out, int out_size, void* d_ws, size_t ws_size,
                              hipStream_t stream)
{
  const float* ray0  = (const float*)d_in[0];
  const float* rdir  = (const float*)d_in[1];
  const float* frand = (const float*)d_in[2];
  const int*   pick  = (const int*)d_in[3];
  Wptrs wp;
  MegaP mp;
  for (int i = 0; i < 8; ++i) {
    wp.w[i] = (const float*)d_in[4 + 2*i];
    mp.b[i] = (const float*)d_in[5 + 2*i];
  }
  mp.w8 = (const float*)d_in[20];
  mp.b8 = (const float*)d_in[21];
  mp.ray0 = ray0; mp.rdir = rdir; mp.frand = frand;

  float* ws = (float*)d_ws;
  float* ptrack = ws;                                   // 8192*24 floats
  unsigned short* WThi = (unsigned short*)(ws + 196608);  // 491520 shorts
  unsigned short* WTlo = WThi + 491520;                   // 491520 shorts
  mp.WThi = WThi; mp.WTlo = WTlo;
  mp.ptrack = ptrack;
  mp.out = (float*)d_out;

  prep_transpose<<<120, 256, 0, stream>>>(wp, WThi, WTlo);
  mega_kernel<<<NR/16, 256, 0, stream>>>(mp);
  gather_kernel<<<NPICK/256, 256, 0, stream>>>(pick, ptrack, mp.out);
}